// Round 6
// baseline (269.910 us; speedup 1.0000x reference)
//
#include <hip/hip_runtime.h>
#include <hip/hip_bf16.h>
#include <stdint.h>

#define IN_F 1024
#define OUT_F 1024
#define NB 8
#define KDIM (IN_F + IN_F * NB)  /* 9216 */
#define NROWS 4096
#define SLICE_ELEMS (NROWS * OUT_F)
#define INIT_BLOCKS (SLICE_ELEMS / (4 * 256))     /* 16384 */
#define PREP_BLOCKS ((NROWS * IN_F) / 256)        /* 16384 */
#define WCONV_BLOCKS ((OUT_F * KDIM) / (4 * 256)) /* 9216  */
#define SPLIT 4
#define KSLICE (KDIM / SPLIT) /* 2304 */

typedef __attribute__((ext_vector_type(8))) short bf16x8;
typedef __attribute__((ext_vector_type(4))) short bf16x4;
typedef __attribute__((ext_vector_type(4))) float f32x4;

// Closed-form uniform cubic B-spline (knots t_j = -2.2 + 0.4j; EPS=1e-8 shift is
// far below bf16 rounding). For x in [t_i,t_{i+1}): 4 nonzero cardinal cubics.
__device__ __forceinline__ void bspline8(float x, float b8[8]) {
  float u = (x + 2.2f) * 2.5f;  // (x - t0)/h
  bool in = (u >= 0.0f) && (u < 11.0f);
  float uc = fminf(fmaxf(u, 0.0f), 10.99f);
  int i = (int)uc;
  float f = uc - (float)i;
  float g = 1.0f - f;
  float f2 = f * f, f3 = f2 * f;
  const float s = 1.0f / 6.0f;
  float v0 = f3 * s;
  float v1 = (-3.0f * f3 + 3.0f * f2 + 3.0f * f + 1.0f) * s;
  float v2 = (3.0f * f3 - 6.0f * f2 + 4.0f) * s;
  float v3 = g * g * g * s;
#pragma unroll
  for (int j = 0; j < 8; ++j) {
    int d = i - j;
    float r = (d == 0) ? v0 : (d == 1) ? v1 : (d == 2) ? v2 : (d == 3) ? v3 : 0.0f;
    b8[j] = in ? r : 0.0f;
  }
}

// One launch: out := bias broadcast (gemm atomically accumulates onto it),
// A := [silu(x) | bspline(x)] bf16, W := [bw | sw] bf16. Branch on blockIdx.
__global__ void prep_all_kernel(const float* __restrict__ x, const float* __restrict__ bw,
                                const float* __restrict__ sw, const float* __restrict__ bb,
                                __hip_bfloat16* __restrict__ A, __hip_bfloat16* __restrict__ W,
                                float* __restrict__ out) {
  if (blockIdx.x < INIT_BLOCKS) {
    int v = blockIdx.x * 256 + threadIdx.x;
    int e = v * 4;
    int o = e & (OUT_F - 1);  // e is a multiple of 4; OUT_F divisible by 4
    *(float4*)(out + e) = *(const float4*)(bb + o);
  } else if (blockIdx.x < INIT_BLOCKS + PREP_BLOCKS) {
    int idx = (blockIdx.x - INIT_BLOCKS) * 256 + threadIdx.x;
    int n = idx >> 10;
    int i = idx & 1023;
    float xv = x[idx];
    float sl = xv / (1.0f + __expf(-xv));
    __hip_bfloat16* row = A + (size_t)n * KDIM;
    row[i] = __float2bfloat16(sl);
    float b8[8];
    bspline8(xv, b8);
    alignas(16) __hip_bfloat16 tmp[8];
#pragma unroll
    for (int c = 0; c < 8; ++c) tmp[c] = __float2bfloat16(b8[c]);
    *(bf16x8*)(row + IN_F + i * 8) = *(const bf16x8*)tmp;
  } else {
    int v = (blockIdx.x - INIT_BLOCKS - PREP_BLOCKS) * 256 + threadIdx.x;
    int e = v * 4;
    int o = e / KDIM;
    int k = e - o * KDIM;
    float4 val = (k < IN_F) ? *(const float4*)(bw + o * IN_F + k)
                            : *(const float4*)(sw + (size_t)o * (IN_F * NB) + (k - IN_F));
    alignas(8) __hip_bfloat16 t[4];
    t[0] = __float2bfloat16(val.x);
    t[1] = __float2bfloat16(val.y);
    t[2] = __float2bfloat16(val.z);
    t[3] = __float2bfloat16(val.w);
    *(bf16x4*)(W + e) = *(const bf16x4*)t;
  }
}

// out += A[4096,9216] @ W[1024,9216]^T, 256x256 tile, BK=64, split-K=4 via fp32
// atomicAdd epilogue (out pre-filled with bias). 512 threads = 8 waves, 2(m)x4(n)
// wave grid, 128x64 per wave -> acc[8][4] (128 VGPRs). Bigger tile halves cache
// re-read traffic vs 128x128 (604 MB total) -- round-5 showed tile re-reads at
// ~8.4 TB/s through L2/L3 were the wall, not prefetch latency.
// Double-buffered LDS 128 KB. Layout per buffer: row-group g (16 rows), k-subtile
// s (32): chunk at (g*2+s)*512 elems in MFMA fragment order (lane l: row=l&15,
// kchunk=l>>4) -> every ds/staging addr = wave-uniform base + 16B*lane
// (conflict-free; legal global_load_lds lane scatter).
__global__ __launch_bounds__(512, 2) void gemm_kernel(const __hip_bfloat16* __restrict__ A,
                                                      const __hip_bfloat16* __restrict__ W,
                                                      float* __restrict__ out) {
  __shared__ __hip_bfloat16 lA[2][256 * 64];
  __shared__ __hip_bfloat16 lB[2][256 * 64];
  const int tid = threadIdx.x;
  const int wave = tid >> 6;  // 0..7
  const int lane = tid & 63;
  const int bm = blockIdx.x * 256;  // 16
  const int bn = blockIdx.y * 256;  // 4
  const int kbeg = blockIdx.z * KSLICE;
  const int iters = KSLICE / 64;    // 36
  const int srow = lane & 15;       // staging row within a 16-row group
  const int skc = (lane >> 4) * 8;  // staging k-chunk offset within a 32-k subtile
  const int wmi = wave & 1;         // m-tile index (0..1) -> 128 rows
  const int wni = wave >> 1;        // n-tile index (0..3) -> 64 cols
  const int r = lane & 15;
  const int quad = lane >> 4;

  // Each wave stages row-groups {2*wave, 2*wave+1} of A and of B (16 groups total).
  const __hip_bfloat16* gA[2];
  const __hip_bfloat16* gB[2];
  gA[0] = A + (size_t)(bm + wave * 32 + srow) * KDIM + kbeg + skc;
  gA[1] = gA[0] + (size_t)16 * KDIM;
  gB[0] = W + (size_t)(bn + wave * 32 + srow) * KDIM + kbeg + skc;
  gB[1] = gB[0] + (size_t)16 * KDIM;

  f32x4 acc[8][4];
#pragma unroll
  for (int a = 0; a < 8; ++a)
#pragma unroll
    for (int b = 0; b < 4; ++b) acc[a][b] = (f32x4){0.f, 0.f, 0.f, 0.f};

#define STAGE(IT, BUF)                                                                           \
  do {                                                                                           \
    const int koff = (IT) * 64;                                                                  \
    _Pragma("unroll") for (int h = 0; h < 2; ++h) {                                              \
      _Pragma("unroll") for (int s = 0; s < 2; ++s) {                                            \
        const __hip_bfloat16* srcA = gA[h] + koff + s * 32;                                      \
        const __hip_bfloat16* srcB = gB[h] + koff + s * 32;                                      \
        __hip_bfloat16* dA = &lA[BUF][((wave * 2 + h) * 2 + s) * 512];                           \
        __hip_bfloat16* dB = &lB[BUF][((wave * 2 + h) * 2 + s) * 512];                           \
        __builtin_amdgcn_global_load_lds((const __attribute__((address_space(1))) void*)srcA,    \
                                         (__attribute__((address_space(3))) void*)dA, 16, 0, 0); \
        __builtin_amdgcn_global_load_lds((const __attribute__((address_space(1))) void*)srcB,    \
                                         (__attribute__((address_space(3))) void*)dB, 16, 0, 0); \
      }                                                                                          \
    }                                                                                            \
  } while (0)

  STAGE(0, 0);
  __syncthreads();

  for (int it = 0; it < iters; ++it) {
    const int p = it & 1;
    if (it + 1 < iters) STAGE(it + 1, p ^ 1);  // in flight across the whole compute phase

#pragma unroll
    for (int s = 0; s < 2; ++s) {
      bf16x8 af[8], bfr[4];
#pragma unroll
      for (int t = 0; t < 8; ++t)
        af[t] = *(const bf16x8*)&lA[p][(((wmi * 8 + t) * 2 + s)) * 512 + lane * 8];
#pragma unroll
      for (int t = 0; t < 4; ++t)
        bfr[t] = *(const bf16x8*)&lB[p][(((wni * 4 + t) * 2 + s)) * 512 + lane * 8];
#pragma unroll
      for (int tm = 0; tm < 8; ++tm)
#pragma unroll
        for (int tn = 0; tn < 4; ++tn)
          acc[tm][tn] =
              __builtin_amdgcn_mfma_f32_16x16x32_bf16(af[tm], bfr[tn], acc[tm][tn], 0, 0, 0);
    }

    __syncthreads();  // drains vmcnt (tile it+1 staged) + all waves done reading buf p
  }
#undef STAGE

  // C/D map: col=lane&15, row=quad*4+reg (m89-verified). Split-K accumulate.
#pragma unroll
  for (int tm = 0; tm < 8; ++tm) {
#pragma unroll
    for (int tn = 0; tn < 4; ++tn) {
      const int col = bn + wni * 64 + tn * 16 + r;
#pragma unroll
      for (int reg = 0; reg < 4; ++reg) {
        const int rowi = bm + wmi * 128 + tm * 16 + quad * 4 + reg;
        atomicAdd(out + (size_t)rowi * OUT_F + col, acc[tm][tn][reg]);
      }
    }
  }
}

// Emergency fallback if ws is too small for A+W (fp32, slow but correct).
__global__ void kan_fallback(const float* __restrict__ x, const float* __restrict__ bw,
                             const float* __restrict__ bb, const float* __restrict__ sw,
                             float* __restrict__ out) {
  __shared__ float act[KDIM];
  int n = blockIdx.x;
  for (int i = threadIdx.x; i < IN_F; i += 256) {
    float xv = x[(size_t)n * IN_F + i];
    act[i] = xv / (1.0f + __expf(-xv));
    float b8[8];
    bspline8(xv, b8);
#pragma unroll
    for (int c = 0; c < 8; ++c) act[IN_F + i * 8 + c] = b8[c];
  }
  __syncthreads();
  for (int o = threadIdx.x; o < OUT_F; o += 256) {
    float s = bb[o];
    const float* wbp = bw + (size_t)o * IN_F;
    for (int k = 0; k < IN_F; ++k) s += act[k] * wbp[k];
    const float* wsp = sw + (size_t)o * (IN_F * NB);
    for (int k = 0; k < IN_F * NB; ++k) s += act[IN_F + k] * wsp[k];
    out[(size_t)n * OUT_F + o] = s;
  }
}

extern "C" void kernel_launch(void* const* d_in, const int* in_sizes, int n_in, void* d_out,
                              int out_size, void* d_ws, size_t ws_size, hipStream_t stream) {
  const float* x = (const float*)d_in[0];
  const float* bw = (const float*)d_in[1];
  const float* bb = (const float*)d_in[2];
  const float* sw = (const float*)d_in[3];
  float* out = (float*)d_out;

  const size_t needA = (size_t)NROWS * KDIM * 2;  // 75.5 MB
  const size_t needW = (size_t)OUT_F * KDIM * 2;  // 18.9 MB
  if (ws_size < needA + needW) {
    kan_fallback<<<NROWS, 256, 0, stream>>>(x, bw, bb, sw, out);
    return;
  }
  __hip_bfloat16* A = (__hip_bfloat16*)d_ws;
  __hip_bfloat16* W = (__hip_bfloat16*)((char*)d_ws + needA);

  prep_all_kernel<<<INIT_BLOCKS + PREP_BLOCKS + WCONV_BLOCKS, 256, 0, stream>>>(x, bw, sw, bb, A,
                                                                                W, out);
  gemm_kernel<<<dim3(NROWS / 256, OUT_F / 256, SPLIT), 512, 0, stream>>>(A, W, out);
}